// Round 7
// baseline (661.648 us; speedup 1.0000x reference)
//
#include <hip/hip_runtime.h>
#include <hip/hip_bf16.h>

typedef __attribute__((ext_vector_type(8))) short short8;
typedef __attribute__((ext_vector_type(4))) float f32x4;

#define T_TOK 2048
#define H_DIM 1024
#define E_NUM 32
#define I_DIM 768
#define TOPK  4
#define NPAIR (T_TOK*TOPK)

// ---- workspace layout (bytes) ----
#define OFF_IDX     0                   // int   [NPAIR]
#define OFF_TKW     (32*1024)           // float [NPAIR]
#define OFF_COUNTS  (64*1024)           // int   [E]
#define OFF_OFFSETS (65*1024)           // int   [E+1]
#define OFF_CURSORS (66*1024)           // int   [E]
#define OFF_PERM    (68*1024)           // int   [NPAIR]
#define OFF_PAIRW   (100*1024)          // float [NPAIR]
#define OFF_POS     (132*1024)          // int   [NPAIR]
#define OFF_XBF     (1024*1024)         // bf16  [T][H]      4 MB
#define OFF_H       (6*1024*1024)       // bf16  [NPAIR][I]  12.6 MB
#define OFF_Y       (20*1024*1024)      // float [NPAIR][H]  33.6 MB

__device__ __forceinline__ unsigned short f2bf(float f) {
    __hip_bfloat16 b = __float2bfloat16(f);
    unsigned short u;
    __builtin_memcpy(&u, &b, 2);
    return u;
}
__device__ __forceinline__ unsigned int pk2(float lo, float hi) {
    return (unsigned int)f2bf(lo) | ((unsigned int)f2bf(hi) << 16);
}

// ---------------- x fp32 -> bf16 ----------------
__global__ __launch_bounds__(256)
void k_xcvt(const float* __restrict__ x, unsigned short* __restrict__ xbf)
{
    int g = blockIdx.x * 256 + threadIdx.x;   // 8 elems per thread
    const float4* p = (const float4*)(x + (size_t)g * 8);
    float4 a = p[0], b = p[1];
    uint4 o = { pk2(a.x,a.y), pk2(a.z,a.w), pk2(b.x,b.y), pk2(b.z,b.w) };
    *(uint4*)(xbf + (size_t)g * 8) = o;
}

// ---------------- router ----------------
__global__ __launch_bounds__(64)
void k_router(const float* __restrict__ x, const float* __restrict__ rw,
              int* __restrict__ idx, float* __restrict__ tkw, int* __restrict__ counts)
{
    int t = blockIdx.x;
    int lane = threadIdx.x;
    const float4* xr = (const float4*)(x + (size_t)t * H_DIM);
    float4 xv[4];
#pragma unroll
    for (int m = 0; m < 4; ++m) xv[m] = xr[m * 64 + lane];

    __shared__ float logits[E_NUM];
    for (int e = 0; e < E_NUM; ++e) {
        const float4* wr = (const float4*)(rw + (size_t)e * H_DIM);
        float acc = 0.f;
#pragma unroll
        for (int m = 0; m < 4; ++m) {
            float4 wv = wr[m * 64 + lane];
            acc += xv[m].x * wv.x + xv[m].y * wv.y + xv[m].z * wv.z + xv[m].w * wv.w;
        }
#pragma unroll
        for (int s = 32; s > 0; s >>= 1) acc += __shfl_xor(acc, s);
        if (lane == 0) logits[e] = acc;
    }
    __syncthreads();
    if (lane == 0) {
        float m = -1e30f;
        for (int e = 0; e < E_NUM; ++e) m = fmaxf(m, logits[e]);
        for (int e = 0; e < E_NUM; ++e) logits[e] = expf(logits[e] - m);
        float vals[TOPK]; int ids[TOPK]; float s = 0.f;
        for (int k = 0; k < TOPK; ++k) {
            float bv = -1.f; int be = 0;
            for (int e = 0; e < E_NUM; ++e)
                if (logits[e] > bv) { bv = logits[e]; be = e; }
            vals[k] = bv; ids[k] = be; logits[be] = -2.f; s += bv;
        }
        float invs = 1.f / s;
        for (int k = 0; k < TOPK; ++k) {
            idx[t * TOPK + k] = ids[k];
            tkw[t * TOPK + k] = vals[k] * invs;
            atomicAdd(&counts[ids[k]], 1);
        }
    }
}

__global__ void k_scan(const int* __restrict__ counts, int* __restrict__ offsets,
                       int* __restrict__ cursors)
{
    if (threadIdx.x == 0) {
        int acc = 0;
        for (int e = 0; e < E_NUM; ++e) { offsets[e] = acc; cursors[e] = acc; acc += counts[e]; }
        offsets[E_NUM] = acc;
    }
}

__global__ __launch_bounds__(256)
void k_scatter(const int* __restrict__ idx, const float* __restrict__ tkw,
               int* __restrict__ cursors, int* __restrict__ perm,
               float* __restrict__ pairw, int* __restrict__ pos)
{
    int g = blockIdx.x * 256 + threadIdx.x;
    if (g >= NPAIR) return;
    int e = idx[g];
    int p = atomicAdd(&cursors[e], 1);
    perm[p] = g >> 2;
    pairw[p] = tkw[g];
    pos[g] = p;
}

// ---------------- gate/up MFMA GEMM + SiLU, reg-prefetch pipelined ----------------
#define GU_BN 64
#define GU_BM 256
#define GU_BK 64
#define PAD   72      // 144 B row stride -> ~2-way bank aliasing (free)
#define GU_NT (H_DIM / GU_BK)   // 16

__global__ __launch_bounds__(256, 2)
void k_gateup(const unsigned short* __restrict__ xbf, const float* __restrict__ gw,
              const float* __restrict__ uw, const int* __restrict__ offsets,
              const int* __restrict__ perm, unsigned short* __restrict__ h)
{
    int e  = blockIdx.z;
    int r0 = offsets[e], r1 = offsets[e + 1];
    int row0 = r0 + blockIdx.y * GU_BM;        // blockIdx.x = N-tile (XCD spread)
    if (row0 >= r1) return;
    int nrows = min(GU_BM, r1 - row0);
    int ib = blockIdx.x * GU_BN;

    __shared__ __align__(16) unsigned short As[GU_BM * PAD];   // 36864 B
    __shared__ __align__(16) unsigned short Bgs[GU_BN * PAD];  //  9216 B
    __shared__ __align__(16) unsigned short Bus[GU_BN * PAD];  //  9216 B
    __shared__ int rtok[GU_BM];

    int tid = threadIdx.x;
    rtok[tid] = perm[min(row0 + tid, r1 - 1)];
    __syncthreads();

    // cache my 8 A-row tokens in registers (kills per-step LDS reads)
    int mytok[8];
#pragma unroll
    for (int p = 0; p < 8; ++p) mytok[p] = rtok[(tid + p * 256) >> 3];
    int akg = tid & 7;                 // my 16B-chunk within the row

    const float* wgb = gw + ((size_t)e * I_DIM + ib) * H_DIM;
    const float* wub = uw + ((size_t)e * I_DIM + ib) * H_DIM;

    int w = tid >> 6;
    int lane = tid & 63;
    int l15 = lane & 15, lhi = lane >> 4;

    f32x4 accg[4][4], accu[4][4];
#pragma unroll
    for (int a = 0; a < 4; ++a)
#pragma unroll
        for (int b = 0; b < 4; ++b) { accg[a][b] = 0.f; accu[a][b] = 0.f; }

    // prefetch registers
    uint4 pa[8];
    float4 pg0[2], pg1[2], pu0[2], pu1[2];

#define GU_LOAD(KB) do {                                                          \
    _Pragma("unroll")                                                             \
    for (int p = 0; p < 8; ++p)                                                   \
        pa[p] = *(const uint4*)(xbf + (size_t)mytok[p] * H_DIM + (KB) + akg * 8); \
    _Pragma("unroll")                                                             \
    for (int it = 0; it < 2; ++it) {                                              \
        int q = tid + it * 256; int brow = q >> 3, bkg = q & 7;                   \
        const float* sg = wgb + (size_t)brow * H_DIM + (KB) + bkg * 8;            \
        pg0[it] = *(const float4*)sg; pg1[it] = *(const float4*)(sg + 4);         \
        const float* su = wub + (size_t)brow * H_DIM + (KB) + bkg * 8;            \
        pu0[it] = *(const float4*)su; pu1[it] = *(const float4*)(su + 4);         \
    } } while (0)

#define GU_WRITE() do {                                                           \
    _Pragma("unroll")                                                             \
    for (int p = 0; p < 8; ++p) {                                                 \
        int arow = (tid + p * 256) >> 3;                                          \
        *(uint4*)&As[arow * PAD + akg * 8] = pa[p];                               \
    }                                                                             \
    _Pragma("unroll")                                                             \
    for (int it = 0; it < 2; ++it) {                                              \
        int q = tid + it * 256; int brow = q >> 3, bkg = q & 7;                   \
        uint4 vg = { pk2(pg0[it].x,pg0[it].y), pk2(pg0[it].z,pg0[it].w),          \
                     pk2(pg1[it].x,pg1[it].y), pk2(pg1[it].z,pg1[it].w) };        \
        *(uint4*)&Bgs[brow * PAD + bkg * 8] = vg;                                 \
        uint4 vu = { pk2(pu0[it].x,pu0[it].y), pk2(pu0[it].z,pu0[it].w),          \
                     pk2(pu1[it].x,pu1[it].y), pk2(pu1[it].z,pu1[it].w) };        \
        *(uint4*)&Bus[brow * PAD + bkg * 8] = vu;                                 \
    } } while (0)

    GU_LOAD(0);
    for (int kt = 0; kt < GU_NT; ++kt) {
        GU_WRITE();                         // waits on in-flight loads, converts, stores to LDS
        __syncthreads();
        if (kt + 1 < GU_NT) GU_LOAD((kt + 1) * GU_BK);   // issue next tile; in flight across compute
#pragma unroll
        for (int kk = 0; kk < 2; ++kk) {
            short8 av[4], bgv[4], buv[4];
            int ko = kk * 32 + lhi * 8;
#pragma unroll
            for (int f = 0; f < 4; ++f) {
                av[f]  = *(const short8*)&As[(w * 64 + f * 16 + l15) * PAD + ko];
                bgv[f] = *(const short8*)&Bgs[(f * 16 + l15) * PAD + ko];
                buv[f] = *(const short8*)&Bus[(f * 16 + l15) * PAD + ko];
            }
#pragma unroll
            for (int fm = 0; fm < 4; ++fm)
#pragma unroll
                for (int fn = 0; fn < 4; ++fn) {
                    accg[fm][fn] = __builtin_amdgcn_mfma_f32_16x16x32_bf16(av[fm], bgv[fn], accg[fm][fn], 0, 0, 0);
                    accu[fm][fn] = __builtin_amdgcn_mfma_f32_16x16x32_bf16(av[fm], buv[fn], accu[fm][fn], 0, 0, 0);
                }
        }
        __syncthreads();
    }
    // epilogue: h = silu(g) * u   (C frag: col = lane&15, row = (lane>>4)*4 + j)
#pragma unroll
    for (int fm = 0; fm < 4; ++fm) {
#pragma unroll
        for (int j = 0; j < 4; ++j) {
            int r = w * 64 + fm * 16 + lhi * 4 + j;
            if (r < nrows) {
                size_t orow = (size_t)(row0 + r) * I_DIM + ib + l15;
#pragma unroll
                for (int fn = 0; fn < 4; ++fn) {
                    float g = accg[fm][fn][j];
                    float u = accu[fm][fn][j];
                    float hv = (g / (1.f + __expf(-g))) * u;
                    h[orow + fn * 16] = f2bf(hv);
                }
            }
        }
    }
}

// ---------------- down MFMA GEMM, reg-prefetch pipelined ----------------
#define DN_BN 64
#define DN_BM 256
#define DN_BK 64
#define DN_NT (I_DIM / DN_BK)   // 12

__global__ __launch_bounds__(256, 2)
void k_down(const float* __restrict__ dw, const int* __restrict__ offsets,
            const float* __restrict__ pairw, const unsigned short* __restrict__ h,
            float* __restrict__ y)
{
    int e  = blockIdx.z;
    int r0 = offsets[e], r1 = offsets[e + 1];
    int row0 = r0 + blockIdx.y * DN_BM;
    if (row0 >= r1) return;
    int nrows = min(DN_BM, r1 - row0);
    int cb = blockIdx.x * DN_BN;

    __shared__ __align__(16) unsigned short As[DN_BM * PAD];
    __shared__ __align__(16) unsigned short Bs[DN_BN * PAD];
    __shared__ float pw[DN_BM];

    int tid = threadIdx.x;
    pw[tid] = pairw[min(row0 + tid, r1 - 1)];
    __syncthreads();

    // my 8 A-row source offsets (clamped rows)
    size_t myar[8];
#pragma unroll
    for (int p = 0; p < 8; ++p) {
        int rr = min(row0 + ((tid + p * 256) >> 3), r1 - 1);
        myar[p] = (size_t)rr * I_DIM;
    }
    int akg = tid & 7;

    const float* wdb = dw + ((size_t)e * H_DIM + cb) * I_DIM;
    int w = tid >> 6, lane = tid & 63;
    int l15 = lane & 15, lhi = lane >> 4;

    f32x4 acc[4][4];
#pragma unroll
    for (int a = 0; a < 4; ++a)
#pragma unroll
        for (int b = 0; b < 4; ++b) acc[a][b] = 0.f;

    uint4 pa[8];
    float4 pd0[2], pd1[2];

#define DN_LOAD(KB) do {                                                     \
    _Pragma("unroll")                                                        \
    for (int p = 0; p < 8; ++p)                                              \
        pa[p] = *(const uint4*)(h + myar[p] + (KB) + akg * 8);               \
    _Pragma("unroll")                                                        \
    for (int it = 0; it < 2; ++it) {                                         \
        int q = tid + it * 256; int brow = q >> 3, bkg = q & 7;              \
        const float* sd = wdb + (size_t)brow * I_DIM + (KB) + bkg * 8;       \
        pd0[it] = *(const float4*)sd; pd1[it] = *(const float4*)(sd + 4);    \
    } } while (0)

#define DN_WRITE() do {                                                      \
    _Pragma("unroll")                                                        \
    for (int p = 0; p < 8; ++p) {                                            \
        int arow = (tid + p * 256) >> 3;                                     \
        *(uint4*)&As[arow * PAD + akg * 8] = pa[p];                          \
    }                                                                        \
    _Pragma("unroll")                                                        \
    for (int it = 0; it < 2; ++it) {                                         \
        int q = tid + it * 256; int brow = q >> 3, bkg = q & 7;              \
        uint4 vd = { pk2(pd0[it].x,pd0[it].y), pk2(pd0[it].z,pd0[it].w),     \
                     pk2(pd1[it].x,pd1[it].y), pk2(pd1[it].z,pd1[it].w) };   \
        *(uint4*)&Bs[brow * PAD + bkg * 8] = vd;                             \
    } } while (0)

    DN_LOAD(0);
    for (int kt = 0; kt < DN_NT; ++kt) {
        DN_WRITE();
        __syncthreads();
        if (kt + 1 < DN_NT) DN_LOAD((kt + 1) * DN_BK);
#pragma unroll
        for (int kk = 0; kk < 2; ++kk) {
            short8 av[4], bv[4];
            int ko = kk * 32 + lhi * 8;
#pragma unroll
            for (int f = 0; f < 4; ++f) {
                av[f] = *(const short8*)&As[(w * 64 + f * 16 + l15) * PAD + ko];
                bv[f] = *(const short8*)&Bs[(f * 16 + l15) * PAD + ko];
            }
#pragma unroll
            for (int fm = 0; fm < 4; ++fm)
#pragma unroll
                for (int fn = 0; fn < 4; ++fn)
                    acc[fm][fn] = __builtin_amdgcn_mfma_f32_16x16x32_bf16(av[fm], bv[fn], acc[fm][fn], 0, 0, 0);
        }
        __syncthreads();
    }
#pragma unroll
    for (int fm = 0; fm < 4; ++fm) {
#pragma unroll
        for (int j = 0; j < 4; ++j) {
            int r = w * 64 + fm * 16 + lhi * 4 + j;
            if (r < nrows) {
                float s = pw[r];
                size_t orow = (size_t)(row0 + r) * H_DIM + cb + l15;
#pragma unroll
                for (int fn = 0; fn < 4; ++fn)
                    y[orow + fn * 16] = s * acc[fm][fn][j];
            }
        }
    }
}

// ---------------- deterministic 4-way combine ----------------
__global__ __launch_bounds__(256)
void k_combine(const float* __restrict__ y, const int* __restrict__ pos,
               float* __restrict__ out)
{
    int g = blockIdx.x * 256 + threadIdx.x;
    int t = g >> 10;
    int hc = g & 1023;
    const int* pp = pos + t * TOPK;
    float s = y[(size_t)pp[0] * H_DIM + hc] + y[(size_t)pp[1] * H_DIM + hc]
            + y[(size_t)pp[2] * H_DIM + hc] + y[(size_t)pp[3] * H_DIM + hc];
    out[g] = s;
}

extern "C" void kernel_launch(void* const* d_in, const int* in_sizes, int n_in,
                              void* d_out, int out_size, void* d_ws, size_t ws_size,
                              hipStream_t stream)
{
    const float* x  = (const float*)d_in[0];   // [1,2048,1024]
    const float* rw = (const float*)d_in[1];   // [32,1024]
    const float* gw = (const float*)d_in[2];   // [32,768,1024]
    const float* uw = (const float*)d_in[3];   // [32,768,1024]
    const float* dw = (const float*)d_in[4];   // [32,1024,768]
    float* out = (float*)d_out;

    char* ws = (char*)d_ws;
    int*   idx     = (int*)  (ws + OFF_IDX);
    float* tkw     = (float*)(ws + OFF_TKW);
    int*   counts  = (int*)  (ws + OFF_COUNTS);
    int*   offsets = (int*)  (ws + OFF_OFFSETS);
    int*   cursors = (int*)  (ws + OFF_CURSORS);
    int*   perm    = (int*)  (ws + OFF_PERM);
    float* pairw   = (float*)(ws + OFF_PAIRW);
    int*   pos     = (int*)  (ws + OFF_POS);
    unsigned short* xbf = (unsigned short*)(ws + OFF_XBF);
    unsigned short* h   = (unsigned short*)(ws + OFF_H);
    float* y            = (float*)(ws + OFF_Y);

    hipMemsetAsync(counts, 0, E_NUM * sizeof(int), stream);

    k_xcvt<<<T_TOK * H_DIM / (256 * 8), 256, 0, stream>>>(x, xbf);
    k_router<<<T_TOK, 64, 0, stream>>>(x, rw, idx, tkw, counts);
    k_scan<<<1, 64, 0, stream>>>(counts, offsets, cursors);
    k_scatter<<<(NPAIR + 255) / 256, 256, 0, stream>>>(idx, tkw, cursors, perm, pairw, pos);

    dim3 g3(I_DIM / GU_BN, NPAIR / GU_BM, E_NUM);   // (12, 32, 32)
    k_gateup<<<g3, 256, 0, stream>>>(xbf, gw, uw, offsets, perm, h);

    dim3 g4(H_DIM / DN_BN, NPAIR / DN_BM, E_NUM);   // (16, 32, 32)
    k_down<<<g4, 256, 0, stream>>>(dw, offsets, pairw, h, y);

    k_combine<<<T_TOK * H_DIM / 256, 256, 0, stream>>>(y, pos, out);
}

// Round 8
// 629.930 us; speedup vs baseline: 1.0504x; 1.0504x over previous
//
#include <hip/hip_runtime.h>
#include <hip/hip_bf16.h>

typedef __attribute__((ext_vector_type(8))) short short8;
typedef __attribute__((ext_vector_type(4))) float f32x4;

#define T_TOK 2048
#define H_DIM 1024
#define E_NUM 32
#define I_DIM 768
#define TOPK  4
#define NPAIR (T_TOK*TOPK)

// ---- workspace layout (bytes) ----
#define OFF_IDX     0                   // int   [NPAIR]
#define OFF_TKW     (32*1024)           // float [NPAIR]
#define OFF_COUNTS  (64*1024)           // int   [E]
#define OFF_OFFSETS (65*1024)           // int   [E+1]
#define OFF_CURSORS (66*1024)           // int   [E]
#define OFF_PERM    (68*1024)           // int   [NPAIR]
#define OFF_PAIRW   (100*1024)          // float [NPAIR]
#define OFF_POS     (132*1024)          // int   [NPAIR]
#define OFF_XBF     (1024*1024)         // bf16  [T][H]      4 MB
#define OFF_H       (6*1024*1024)       // bf16  [NPAIR][I]  12.6 MB
#define OFF_Y       (20*1024*1024)      // float [NPAIR][H]  33.6 MB

__device__ __forceinline__ unsigned short f2bf(float f) {
    __hip_bfloat16 b = __float2bfloat16(f);
    unsigned short u;
    __builtin_memcpy(&u, &b, 2);
    return u;
}
__device__ __forceinline__ unsigned int pk2(float lo, float hi) {
    return (unsigned int)f2bf(lo) | ((unsigned int)f2bf(hi) << 16);
}

// ---------------- x fp32 -> bf16 ----------------
__global__ __launch_bounds__(256)
void k_xcvt(const float* __restrict__ x, unsigned short* __restrict__ xbf)
{
    int g = blockIdx.x * 256 + threadIdx.x;   // 8 elems per thread
    const float4* p = (const float4*)(x + (size_t)g * 8);
    float4 a = p[0], b = p[1];
    uint4 o = { pk2(a.x,a.y), pk2(a.z,a.w), pk2(b.x,b.y), pk2(b.z,b.w) };
    *(uint4*)(xbf + (size_t)g * 8) = o;
}

// ---------------- router ----------------
__global__ __launch_bounds__(64)
void k_router(const float* __restrict__ x, const float* __restrict__ rw,
              int* __restrict__ idx, float* __restrict__ tkw, int* __restrict__ counts)
{
    int t = blockIdx.x;
    int lane = threadIdx.x;
    const float4* xr = (const float4*)(x + (size_t)t * H_DIM);
    float4 xv[4];
#pragma unroll
    for (int m = 0; m < 4; ++m) xv[m] = xr[m * 64 + lane];

    __shared__ float logits[E_NUM];
    for (int e = 0; e < E_NUM; ++e) {
        const float4* wr = (const float4*)(rw + (size_t)e * H_DIM);
        float acc = 0.f;
#pragma unroll
        for (int m = 0; m < 4; ++m) {
            float4 wv = wr[m * 64 + lane];
            acc += xv[m].x * wv.x + xv[m].y * wv.y + xv[m].z * wv.z + xv[m].w * wv.w;
        }
#pragma unroll
        for (int s = 32; s > 0; s >>= 1) acc += __shfl_xor(acc, s);
        if (lane == 0) logits[e] = acc;
    }
    __syncthreads();
    if (lane == 0) {
        float m = -1e30f;
        for (int e = 0; e < E_NUM; ++e) m = fmaxf(m, logits[e]);
        for (int e = 0; e < E_NUM; ++e) logits[e] = expf(logits[e] - m);
        float vals[TOPK]; int ids[TOPK]; float s = 0.f;
        for (int k = 0; k < TOPK; ++k) {
            float bv = -1.f; int be = 0;
            for (int e = 0; e < E_NUM; ++e)
                if (logits[e] > bv) { bv = logits[e]; be = e; }
            vals[k] = bv; ids[k] = be; logits[be] = -2.f; s += bv;
        }
        float invs = 1.f / s;
        for (int k = 0; k < TOPK; ++k) {
            idx[t * TOPK + k] = ids[k];
            tkw[t * TOPK + k] = vals[k] * invs;
            atomicAdd(&counts[ids[k]], 1);
        }
    }
}

__global__ void k_scan(const int* __restrict__ counts, int* __restrict__ offsets,
                       int* __restrict__ cursors)
{
    if (threadIdx.x == 0) {
        int acc = 0;
        for (int e = 0; e < E_NUM; ++e) { offsets[e] = acc; cursors[e] = acc; acc += counts[e]; }
        offsets[E_NUM] = acc;
    }
}

__global__ __launch_bounds__(256)
void k_scatter(const int* __restrict__ idx, const float* __restrict__ tkw,
               int* __restrict__ cursors, int* __restrict__ perm,
               float* __restrict__ pairw, int* __restrict__ pos)
{
    int g = blockIdx.x * 256 + threadIdx.x;
    if (g >= NPAIR) return;
    int e = idx[g];
    int p = atomicAdd(&cursors[e], 1);
    perm[p] = g >> 2;
    pairw[p] = tkw[g];
    pos[g] = p;
}

// ============ gate/up GEMM: barrier-free, wave-private B staging ============
// A fragments are lane-exclusive -> loaded directly from L2/L3-resident xbf.
// B (fp32 weights) staged per-wave into private LDS (fp32->bf16 in staging).
// No __syncthreads anywhere: waves free-run, TLP keeps HBM queues full.
#define GU_BN 64
#define GU_BM 256
#define GU_BK 64
#define PAD   72                 // 144 B row stride -> 2-way bank aliasing (free, r6-measured)
#define GU_NT (H_DIM / GU_BK)    // 16
#define WB    (GU_BN * PAD)      // 4608 bf16 elems per wave-buffer (9216 B)

__global__ __launch_bounds__(256, 2)
void k_gateup(const unsigned short* __restrict__ xbf, const float* __restrict__ gw,
              const float* __restrict__ uw, const int* __restrict__ offsets,
              const int* __restrict__ perm, unsigned short* __restrict__ h)
{
    int e  = blockIdx.z;
    int r0 = offsets[e], r1 = offsets[e + 1];
    int row0 = r0 + blockIdx.y * GU_BM;        // blockIdx.x = N-tile (XCD spread)
    if (row0 >= r1) return;
    int nrows = min(GU_BM, r1 - row0);
    int ib = blockIdx.x * GU_BN;

    extern __shared__ __align__(16) unsigned short smem[];   // 4 waves * 2 * WB
    int tid = threadIdx.x, w = tid >> 6, lane = tid & 63;
    unsigned short* bg = smem + (size_t)w * (2 * WB);
    unsigned short* bu = bg + WB;
    int l15 = lane & 15, lhi = lane >> 4;

    // my 4 A-row bases (lane-exclusive fragment rows, clamped)
    size_t arow[4];
#pragma unroll
    for (int fm = 0; fm < 4; ++fm) {
        int r = w * 64 + fm * 16 + l15;
        arow[fm] = (size_t)perm[min(row0 + r, r1 - 1)] * H_DIM;
    }

    const float* wgb = gw + ((size_t)e * I_DIM + ib) * H_DIM;
    const float* wub = uw + ((size_t)e * I_DIM + ib) * H_DIM;

    int srow = lane >> 3;          // 0..7   (staging row within 8-row group)
    int sc   = (lane & 7) * 8;     // elem offset: 8 elems = 32B fp32 / 16B bf16

    f32x4 accg[4][4], accu[4][4];
#pragma unroll
    for (int a = 0; a < 4; ++a)
#pragma unroll
        for (int b = 0; b < 4; ++b) { accg[a][b] = 0.f; accu[a][b] = 0.f; }

    // per-wave stage: 64 rows x 64 k, fp32 -> bf16; 256B-contiguous segments per row
#define GU_STAGE(KB) do {                                                              \
    _Pragma("unroll 4")                                                                \
    for (int rr = 0; rr < 8; ++rr) {                                                   \
        int row = rr * 8 + srow;                                                       \
        const float* sg = wgb + (size_t)row * H_DIM + (KB) + sc;                       \
        float4 g0 = *(const float4*)sg, g1 = *(const float4*)(sg + 4);                 \
        const float* su = wub + (size_t)row * H_DIM + (KB) + sc;                       \
        float4 u0 = *(const float4*)su, u1 = *(const float4*)(su + 4);                 \
        uint4 vg = { pk2(g0.x,g0.y), pk2(g0.z,g0.w), pk2(g1.x,g1.y), pk2(g1.z,g1.w) }; \
        *(uint4*)&bg[row * PAD + sc] = vg;                                             \
        uint4 vu = { pk2(u0.x,u0.y), pk2(u0.z,u0.w), pk2(u1.x,u1.y), pk2(u1.z,u1.w) }; \
        *(uint4*)&bu[row * PAD + sc] = vu;                                             \
    } } while (0)

    GU_STAGE(0);
    for (int kt = 0; kt < GU_NT; ++kt) {
        int kb = kt * GU_BK;
        // A fragments: direct global loads (xbf is L2/L3-resident, 4 MB)
        short8 av[4][2];
#pragma unroll
        for (int fm = 0; fm < 4; ++fm)
#pragma unroll
            for (int kk = 0; kk < 2; ++kk)
                av[fm][kk] = *(const short8*)(xbf + arow[fm] + kb + kk * 32 + lhi * 8);
#pragma unroll
        for (int kk = 0; kk < 2; ++kk) {
            short8 bgv[4], buv[4];
            int ko = kk * 32 + lhi * 8;
#pragma unroll
            for (int f = 0; f < 4; ++f) {
                bgv[f] = *(const short8*)&bg[(f * 16 + l15) * PAD + ko];
                buv[f] = *(const short8*)&bu[(f * 16 + l15) * PAD + ko];
            }
#pragma unroll
            for (int fm = 0; fm < 4; ++fm)
#pragma unroll
                for (int fn = 0; fn < 4; ++fn) {
                    accg[fm][fn] = __builtin_amdgcn_mfma_f32_16x16x32_bf16(av[fm][kk], bgv[fn], accg[fm][fn], 0, 0, 0);
                    accu[fm][fn] = __builtin_amdgcn_mfma_f32_16x16x32_bf16(av[fm][kk], buv[fn], accu[fm][fn], 0, 0, 0);
                }
        }
        if (kt + 1 < GU_NT) GU_STAGE(kb + GU_BK);   // same-wave DS is in-order: no barrier needed
    }
    // epilogue: h = silu(g) * u   (C frag: col = lane&15, row = (lane>>4)*4 + j)
#pragma unroll
    for (int fm = 0; fm < 4; ++fm) {
#pragma unroll
        for (int j = 0; j < 4; ++j) {
            int r = w * 64 + fm * 16 + lhi * 4 + j;
            if (r < nrows) {
                size_t orow = (size_t)(row0 + r) * I_DIM + ib + l15;
#pragma unroll
                for (int fn = 0; fn < 4; ++fn) {
                    float g = accg[fm][fn][j];
                    float u = accu[fm][fn][j];
                    float hv = (g / (1.f + __expf(-g))) * u;
                    h[orow + fn * 16] = f2bf(hv);
                }
            }
        }
    }
}

// ============ down GEMM: barrier-free, wave-private B staging ============
#define DN_BN 64
#define DN_BM 256
#define DN_BK 64
#define DN_NT (I_DIM / DN_BK)   // 12
#define WBD   (DN_BN * PAD)

__global__ __launch_bounds__(256, 2)
void k_down(const float* __restrict__ dw, const int* __restrict__ offsets,
            const float* __restrict__ pairw, const unsigned short* __restrict__ h,
            float* __restrict__ y)
{
    int e  = blockIdx.z;
    int r0 = offsets[e], r1 = offsets[e + 1];
    int row0 = r0 + blockIdx.y * DN_BM;
    if (row0 >= r1) return;
    int nrows = min(DN_BM, r1 - row0);
    int cb = blockIdx.x * DN_BN;

    __shared__ __align__(16) unsigned short smemd[4 * WBD];  // 36864 B
    int tid = threadIdx.x, w = tid >> 6, lane = tid & 63;
    unsigned short* bd = smemd + (size_t)w * WBD;
    int l15 = lane & 15, lhi = lane >> 4;

    size_t arow[4];
#pragma unroll
    for (int fm = 0; fm < 4; ++fm) {
        int r = w * 64 + fm * 16 + l15;
        arow[fm] = (size_t)min(row0 + r, r1 - 1) * I_DIM;
    }

    const float* wdb = dw + ((size_t)e * H_DIM + cb) * I_DIM;
    int srow = lane >> 3;
    int sc   = (lane & 7) * 8;

    f32x4 acc[4][4];
#pragma unroll
    for (int a = 0; a < 4; ++a)
#pragma unroll
        for (int b = 0; b < 4; ++b) acc[a][b] = 0.f;

#define DN_STAGE(KB) do {                                                              \
    _Pragma("unroll 4")                                                                \
    for (int rr = 0; rr < 8; ++rr) {                                                   \
        int row = rr * 8 + srow;                                                       \
        const float* sd = wdb + (size_t)row * I_DIM + (KB) + sc;                       \
        float4 d0 = *(const float4*)sd, d1 = *(const float4*)(sd + 4);                 \
        uint4 vd = { pk2(d0.x,d0.y), pk2(d0.z,d0.w), pk2(d1.x,d1.y), pk2(d1.z,d1.w) }; \
        *(uint4*)&bd[row * PAD + sc] = vd;                                             \
    } } while (0)

    DN_STAGE(0);
    for (int kt = 0; kt < DN_NT; ++kt) {
        int kb = kt * DN_BK;
        short8 av[4][2];
#pragma unroll
        for (int fm = 0; fm < 4; ++fm)
#pragma unroll
            for (int kk = 0; kk < 2; ++kk)
                av[fm][kk] = *(const short8*)(h + arow[fm] + kb + kk * 32 + lhi * 8);
#pragma unroll
        for (int kk = 0; kk < 2; ++kk) {
            short8 bv[4];
            int ko = kk * 32 + lhi * 8;
#pragma unroll
            for (int f = 0; f < 4; ++f)
                bv[f] = *(const short8*)&bd[(f * 16 + l15) * PAD + ko];
#pragma unroll
            for (int fm = 0; fm < 4; ++fm)
#pragma unroll
                for (int fn = 0; fn < 4; ++fn)
                    acc[fm][fn] = __builtin_amdgcn_mfma_f32_16x16x32_bf16(av[fm][kk], bv[fn], acc[fm][fn], 0, 0, 0);
        }
        if (kt + 1 < DN_NT) DN_STAGE(kb + DN_BK);
    }
#pragma unroll
    for (int fm = 0; fm < 4; ++fm) {
#pragma unroll
        for (int j = 0; j < 4; ++j) {
            int r = w * 64 + fm * 16 + lhi * 4 + j;
            if (r < nrows) {
                float s = pairw[row0 + r];
                size_t orow = (size_t)(row0 + r) * H_DIM + cb + l15;
#pragma unroll
                for (int fn = 0; fn < 4; ++fn)
                    y[orow + fn * 16] = s * acc[fm][fn][j];
            }
        }
    }
}

// ---------------- deterministic 4-way combine ----------------
__global__ __launch_bounds__(256)
void k_combine(const float* __restrict__ y, const int* __restrict__ pos,
               float* __restrict__ out)
{
    int g = blockIdx.x * 256 + threadIdx.x;
    int t = g >> 10;
    int hc = g & 1023;
    const int* pp = pos + t * TOPK;
    float s = y[(size_t)pp[0] * H_DIM + hc] + y[(size_t)pp[1] * H_DIM + hc]
            + y[(size_t)pp[2] * H_DIM + hc] + y[(size_t)pp[3] * H_DIM + hc];
    out[g] = s;
}

extern "C" void kernel_launch(void* const* d_in, const int* in_sizes, int n_in,
                              void* d_out, int out_size, void* d_ws, size_t ws_size,
                              hipStream_t stream)
{
    const float* x  = (const float*)d_in[0];   // [1,2048,1024]
    const float* rw = (const float*)d_in[1];   // [32,1024]
    const float* gw = (const float*)d_in[2];   // [32,768,1024]
    const float* uw = (const float*)d_in[3];   // [32,768,1024]
    const float* dw = (const float*)d_in[4];   // [32,1024,768]
    float* out = (float*)d_out;

    char* ws = (char*)d_ws;
    int*   idx     = (int*)  (ws + OFF_IDX);
    float* tkw     = (float*)(ws + OFF_TKW);
    int*   counts  = (int*)  (ws + OFF_COUNTS);
    int*   offsets = (int*)  (ws + OFF_OFFSETS);
    int*   cursors = (int*)  (ws + OFF_CURSORS);
    int*   perm    = (int*)  (ws + OFF_PERM);
    float* pairw   = (float*)(ws + OFF_PAIRW);
    int*   pos     = (int*)  (ws + OFF_POS);
    unsigned short* xbf = (unsigned short*)(ws + OFF_XBF);
    unsigned short* h   = (unsigned short*)(ws + OFF_H);
    float* y            = (float*)(ws + OFF_Y);

    hipMemsetAsync(counts, 0, E_NUM * sizeof(int), stream);

    k_xcvt<<<T_TOK * H_DIM / (256 * 8), 256, 0, stream>>>(x, xbf);
    k_router<<<T_TOK, 64, 0, stream>>>(x, rw, idx, tkw, counts);
    k_scan<<<1, 64, 0, stream>>>(counts, offsets, cursors);
    k_scatter<<<(NPAIR + 255) / 256, 256, 0, stream>>>(idx, tkw, cursors, perm, pairw, pos);

    dim3 g3(I_DIM / GU_BN, NPAIR / GU_BM, E_NUM);   // (12, 32, 32)
    k_gateup<<<g3, 256, 4 * 2 * WB * sizeof(unsigned short), stream>>>(xbf, gw, uw, offsets, perm, h);

    dim3 g4(H_DIM / DN_BN, NPAIR / DN_BM, E_NUM);   // (16, 32, 32)
    k_down<<<g4, 256, 0, stream>>>(dw, offsets, pairw, h, y);

    k_combine<<<T_TOK * H_DIM / 256, 256, 0, stream>>>(y, pos, out);
}

// Round 11
// 498.824 us; speedup vs baseline: 1.3264x; 1.2628x over previous
//
#include <hip/hip_runtime.h>
#include <hip/hip_bf16.h>

typedef __attribute__((ext_vector_type(8))) short short8;
typedef __attribute__((ext_vector_type(4))) float f32x4;

#define T_TOK 2048
#define H_DIM 1024
#define E_NUM 32
#define I_DIM 768
#define TOPK  4
#define NPAIR (T_TOK*TOPK)

// ---- workspace layout (bytes) ----
#define OFF_IDX     0                   // int   [NPAIR]
#define OFF_TKW     (32*1024)           // float [NPAIR]
#define OFF_COUNTS  (64*1024)           // int   [E]
#define OFF_OFFSETS (65*1024)           // int   [E+1]
#define OFF_CURSORS (66*1024)           // int   [E]
#define OFF_PERM    (68*1024)           // int   [NPAIR]
#define OFF_PAIRW   (100*1024)          // float [NPAIR]
#define OFF_XBF     (1024*1024)         // bf16  [T][H]      4 MB
#define OFF_H       (6*1024*1024)       // bf16  [NPAIR][I]  12.6 MB

__device__ __forceinline__ unsigned short f2bf(float f) {
    __hip_bfloat16 b = __float2bfloat16(f);
    unsigned short u;
    __builtin_memcpy(&u, &b, 2);
    return u;
}
__device__ __forceinline__ unsigned int pk2(float lo, float hi) {
    return (unsigned int)f2bf(lo) | ((unsigned int)f2bf(hi) << 16);
}

// ---------------- x fp32 -> bf16 ----------------
__global__ __launch_bounds__(256)
void k_xcvt(const float* __restrict__ x, unsigned short* __restrict__ xbf)
{
    int g = blockIdx.x * 256 + threadIdx.x;   // 8 elems per thread
    const float4* p = (const float4*)(x + (size_t)g * 8);
    float4 a = p[0], b = p[1];
    uint4 o = { pk2(a.x,a.y), pk2(a.z,a.w), pk2(b.x,b.y), pk2(b.z,b.w) };
    *(uint4*)(xbf + (size_t)g * 8) = o;
}

// ---------------- router (fp32 exact: expert selection must match reference) ----
__global__ __launch_bounds__(64)
void k_router(const float* __restrict__ x, const float* __restrict__ rw,
              int* __restrict__ idx, float* __restrict__ tkw, int* __restrict__ counts)
{
    int t = blockIdx.x;
    int lane = threadIdx.x;
    const float4* xr = (const float4*)(x + (size_t)t * H_DIM);
    float4 xv[4];
#pragma unroll
    for (int m = 0; m < 4; ++m) xv[m] = xr[m * 64 + lane];

    __shared__ float logits[E_NUM];
    for (int e = 0; e < E_NUM; ++e) {
        const float4* wr = (const float4*)(rw + (size_t)e * H_DIM);
        float acc = 0.f;
#pragma unroll
        for (int m = 0; m < 4; ++m) {
            float4 wv = wr[m * 64 + lane];
            acc += xv[m].x * wv.x + xv[m].y * wv.y + xv[m].z * wv.z + xv[m].w * wv.w;
        }
#pragma unroll
        for (int s = 32; s > 0; s >>= 1) acc += __shfl_xor(acc, s);
        if (lane == 0) logits[e] = acc;
    }
    __syncthreads();
    if (lane == 0) {
        float m = -1e30f;
        for (int e = 0; e < E_NUM; ++e) m = fmaxf(m, logits[e]);
        for (int e = 0; e < E_NUM; ++e) logits[e] = expf(logits[e] - m);
        float vals[TOPK]; int ids[TOPK]; float s = 0.f;
        for (int k = 0; k < TOPK; ++k) {
            float bv = -1.f; int be = 0;
            for (int e = 0; e < E_NUM; ++e)
                if (logits[e] > bv) { bv = logits[e]; be = e; }
            vals[k] = bv; ids[k] = be; logits[be] = -2.f; s += bv;
        }
        float invs = 1.f / s;
        for (int k = 0; k < TOPK; ++k) {
            idx[t * TOPK + k] = ids[k];
            tkw[t * TOPK + k] = vals[k] * invs;
            atomicAdd(&counts[ids[k]], 1);
        }
    }
}

__global__ void k_scan(const int* __restrict__ counts, int* __restrict__ offsets,
                       int* __restrict__ cursors)
{
    if (threadIdx.x == 0) {
        int acc = 0;
        for (int e = 0; e < E_NUM; ++e) { offsets[e] = acc; cursors[e] = acc; acc += counts[e]; }
        offsets[E_NUM] = acc;
    }
}

__global__ __launch_bounds__(256)
void k_scatter(const int* __restrict__ idx, const float* __restrict__ tkw,
               int* __restrict__ cursors, int* __restrict__ perm,
               float* __restrict__ pairw)
{
    int g = blockIdx.x * 256 + threadIdx.x;
    if (g >= NPAIR) return;
    int e = idx[g];
    int p = atomicAdd(&cursors[e], 1);
    perm[p] = g >> 2;
    pairw[p] = tkw[g];
}

// ============ gate/up MFMA GEMM + SiLU (r6 template, BM=128 for occupancy) ====
#define GU_BN 64
#define GU_BM 128
#define GU_BK 64
#define PAD   72      // 144 B row stride -> 2-way bank aliasing (free, r6-measured)
#define GU_NT (H_DIM / GU_BK)   // 16

__global__ __launch_bounds__(256, 3)
void k_gateup(const unsigned short* __restrict__ xbf, const float* __restrict__ gw,
              const float* __restrict__ uw, const int* __restrict__ offsets,
              const int* __restrict__ perm, unsigned short* __restrict__ h)
{
    int e  = blockIdx.z;
    int r0 = offsets[e], r1 = offsets[e + 1];
    int row0 = r0 + blockIdx.y * GU_BM;        // blockIdx.x = N-tile
    if (row0 >= r1) return;
    int nrows = min(GU_BM, r1 - row0);
    int ib = blockIdx.x * GU_BN;

    __shared__ __align__(16) unsigned short As[GU_BM * PAD];   // 18432 B
    __shared__ __align__(16) unsigned short Bgs[GU_BN * PAD];  //  9216 B
    __shared__ __align__(16) unsigned short Bus[GU_BN * PAD];  //  9216 B
    __shared__ int rtok[GU_BM];

    int tid = threadIdx.x;
    if (tid < GU_BM) rtok[tid] = perm[min(row0 + tid, r1 - 1)];
    __syncthreads();

    // cache my 4 A-row tokens (A tile = 128 rows x 8 chunks = 1024 chunks / 256 thr)
    int mytok[4];
#pragma unroll
    for (int p = 0; p < 4; ++p) mytok[p] = rtok[(tid + p * 256) >> 3];
    int akg = tid & 7;

    const float* wgb = gw + ((size_t)e * I_DIM + ib) * H_DIM;
    const float* wub = uw + ((size_t)e * I_DIM + ib) * H_DIM;

    int w = tid >> 6;
    int lane = tid & 63;
    int l15 = lane & 15, lhi = lane >> 4;

    f32x4 accg[2][4], accu[2][4];
#pragma unroll
    for (int a = 0; a < 2; ++a)
#pragma unroll
        for (int b = 0; b < 4; ++b) { accg[a][b] = 0.f; accu[a][b] = 0.f; }

    for (int kb = 0; kb < H_DIM; kb += GU_BK) {
        __syncthreads();
        // A: 128 rows x 64 k bf16 (gathered)
#pragma unroll
        for (int p = 0; p < 4; ++p) {
            int q = tid + p * 256;
            int row = q >> 3;
            uint4 v = *(const uint4*)(xbf + (size_t)mytok[p] * H_DIM + kb + akg * 8);
            *(uint4*)&As[row * PAD + akg * 8] = v;
        }
        // B gate/up: 64 rows x 64 k fp32 -> bf16 in staging
#pragma unroll
        for (int p = 0; p < 2; ++p) {
            int q = tid + p * 256;
            int row = q >> 3, kg = q & 7;
            const float* sg = wgb + (size_t)row * H_DIM + kb + kg * 8;
            float4 a0 = *(const float4*)sg, a1 = *(const float4*)(sg + 4);
            uint4 vg = { pk2(a0.x,a0.y), pk2(a0.z,a0.w), pk2(a1.x,a1.y), pk2(a1.z,a1.w) };
            *(uint4*)&Bgs[row * PAD + kg * 8] = vg;
            const float* su = wub + (size_t)row * H_DIM + kb + kg * 8;
            float4 b0 = *(const float4*)su, b1 = *(const float4*)(su + 4);
            uint4 vu = { pk2(b0.x,b0.y), pk2(b0.z,b0.w), pk2(b1.x,b1.y), pk2(b1.z,b1.w) };
            *(uint4*)&Bus[row * PAD + kg * 8] = vu;
        }
        __syncthreads();
#pragma unroll
        for (int kk = 0; kk < 2; ++kk) {
            short8 av[2], bgv[4], buv[4];
            int ko = kk * 32 + lhi * 8;
#pragma unroll
            for (int f = 0; f < 2; ++f)
                av[f]  = *(const short8*)&As[(w * 32 + f * 16 + l15) * PAD + ko];
#pragma unroll
            for (int f = 0; f < 4; ++f) {
                bgv[f] = *(const short8*)&Bgs[(f * 16 + l15) * PAD + ko];
                buv[f] = *(const short8*)&Bus[(f * 16 + l15) * PAD + ko];
            }
#pragma unroll
            for (int fm = 0; fm < 2; ++fm)
#pragma unroll
                for (int fn = 0; fn < 4; ++fn) {
                    accg[fm][fn] = __builtin_amdgcn_mfma_f32_16x16x32_bf16(av[fm], bgv[fn], accg[fm][fn], 0, 0, 0);
                    accu[fm][fn] = __builtin_amdgcn_mfma_f32_16x16x32_bf16(av[fm], buv[fn], accu[fm][fn], 0, 0, 0);
                }
        }
    }
    // epilogue: h = silu(g) * u   (C frag: col = lane&15, row = (lane>>4)*4 + j)
#pragma unroll
    for (int fm = 0; fm < 2; ++fm) {
#pragma unroll
        for (int j = 0; j < 4; ++j) {
            int r = w * 32 + fm * 16 + lhi * 4 + j;
            if (r < nrows) {
                size_t orow = (size_t)(row0 + r) * I_DIM + ib + l15;
#pragma unroll
                for (int fn = 0; fn < 4; ++fn) {
                    float g = accg[fm][fn][j];
                    float u = accu[fm][fn][j];
                    float hv = (g / (1.f + __expf(-g))) * u;
                    h[orow + fn * 16] = f2bf(hv);
                }
            }
        }
    }
}

// ============ down MFMA GEMM, fused scale + atomic combine into out ==========
#define DN_BN 64
#define DN_BM 128
#define DN_BK 64
#define DN_NT (I_DIM / DN_BK)   // 12

__global__ __launch_bounds__(256, 3)
void k_down(const float* __restrict__ dw, const int* __restrict__ offsets,
            const float* __restrict__ pairw, const int* __restrict__ perm,
            const unsigned short* __restrict__ h, float* __restrict__ out)
{
    int e  = blockIdx.z;
    int r0 = offsets[e], r1 = offsets[e + 1];
    int row0 = r0 + blockIdx.y * DN_BM;
    if (row0 >= r1) return;
    int nrows = min(DN_BM, r1 - row0);
    int cb = blockIdx.x * DN_BN;

    __shared__ __align__(16) unsigned short As[DN_BM * PAD];   // 18432 B
    __shared__ __align__(16) unsigned short Bs[DN_BN * PAD];   //  9216 B
    __shared__ float pw[DN_BM];
    __shared__ int   ptok[DN_BM];

    int tid = threadIdx.x;
    if (tid < DN_BM) {
        int rr = min(row0 + tid, r1 - 1);
        pw[tid]   = pairw[rr];
        ptok[tid] = perm[rr];
    }
    __syncthreads();

    size_t myar[4];
#pragma unroll
    for (int p = 0; p < 4; ++p) {
        int rr = min(row0 + ((tid + p * 256) >> 3), r1 - 1);
        myar[p] = (size_t)rr * I_DIM;
    }
    int akg = tid & 7;

    const float* wdb = dw + ((size_t)e * H_DIM + cb) * I_DIM;
    int w = tid >> 6, lane = tid & 63;
    int l15 = lane & 15, lhi = lane >> 4;

    f32x4 acc[2][4];
#pragma unroll
    for (int a = 0; a < 2; ++a)
#pragma unroll
        for (int b = 0; b < 4; ++b) acc[a][b] = 0.f;

    for (int kb = 0; kb < I_DIM; kb += DN_BK) {
        __syncthreads();
#pragma unroll
        for (int p = 0; p < 4; ++p) {
            int q = tid + p * 256;
            int row = q >> 3;
            uint4 v = *(const uint4*)(h + myar[p] + kb + akg * 8);
            *(uint4*)&As[row * PAD + akg * 8] = v;
        }
#pragma unroll
        for (int p = 0; p < 2; ++p) {
            int q = tid + p * 256;
            int row = q >> 3, kg = q & 7;
            const float* sd = wdb + (size_t)row * I_DIM + kb + kg * 8;
            float4 a0 = *(const float4*)sd, a1 = *(const float4*)(sd + 4);
            uint4 vd = { pk2(a0.x,a0.y), pk2(a0.z,a0.w), pk2(a1.x,a1.y), pk2(a1.z,a1.w) };
            *(uint4*)&Bs[row * PAD + kg * 8] = vd;
        }
        __syncthreads();
#pragma unroll
        for (int kk = 0; kk < 2; ++kk) {
            short8 av[2], bv[4];
            int ko = kk * 32 + lhi * 8;
#pragma unroll
            for (int f = 0; f < 2; ++f)
                av[f] = *(const short8*)&As[(w * 32 + f * 16 + l15) * PAD + ko];
#pragma unroll
            for (int f = 0; f < 4; ++f)
                bv[f] = *(const short8*)&Bs[(f * 16 + l15) * PAD + ko];
#pragma unroll
            for (int fm = 0; fm < 2; ++fm)
#pragma unroll
                for (int fn = 0; fn < 4; ++fn)
                    acc[fm][fn] = __builtin_amdgcn_mfma_f32_16x16x32_bf16(av[fm], bv[fn], acc[fm][fn], 0, 0, 0);
        }
    }
    // epilogue: out[token] += pw * acc   (atomic 4-way combine; order-noise ~1e-6 << tol)
#pragma unroll
    for (int fm = 0; fm < 2; ++fm) {
#pragma unroll
        for (int j = 0; j < 4; ++j) {
            int r = w * 32 + fm * 16 + lhi * 4 + j;
            if (r < nrows) {
                float s = pw[r];
                float* obase = out + (size_t)ptok[r] * H_DIM + cb + l15;
#pragma unroll
                for (int fn = 0; fn < 4; ++fn)
                    atomicAdd(obase + fn * 16, s * acc[fm][fn][j]);
            }
        }
    }
}

extern "C" void kernel_launch(void* const* d_in, const int* in_sizes, int n_in,
                              void* d_out, int out_size, void* d_ws, size_t ws_size,
                              hipStream_t stream)
{
    const float* x  = (const float*)d_in[0];   // [1,2048,1024]
    const float* rw = (const float*)d_in[1];   // [32,1024]
    const float* gw = (const float*)d_in[2];   // [32,768,1024]
    const float* uw = (const float*)d_in[3];   // [32,768,1024]
    const float* dw = (const float*)d_in[4];   // [32,1024,768]
    float* out = (float*)d_out;

    char* ws = (char*)d_ws;
    int*   idx     = (int*)  (ws + OFF_IDX);
    float* tkw     = (float*)(ws + OFF_TKW);
    int*   counts  = (int*)  (ws + OFF_COUNTS);
    int*   offsets = (int*)  (ws + OFF_OFFSETS);
    int*   cursors = (int*)  (ws + OFF_CURSORS);
    int*   perm    = (int*)  (ws + OFF_PERM);
    float* pairw   = (float*)(ws + OFF_PAIRW);
    unsigned short* xbf = (unsigned short*)(ws + OFF_XBF);
    unsigned short* h   = (unsigned short*)(ws + OFF_H);

    hipMemsetAsync(counts, 0, E_NUM * sizeof(int), stream);
    hipMemsetAsync(out, 0, (size_t)T_TOK * H_DIM * sizeof(float), stream);

    k_xcvt<<<T_TOK * H_DIM / (256 * 8), 256, 0, stream>>>(x, xbf);
    k_router<<<T_TOK, 64, 0, stream>>>(x, rw, idx, tkw, counts);
    k_scan<<<1, 64, 0, stream>>>(counts, offsets, cursors);
    k_scatter<<<(NPAIR + 255) / 256, 256, 0, stream>>>(idx, tkw, cursors, perm, pairw);

    dim3 g3(I_DIM / GU_BN, NPAIR / GU_BM, E_NUM);   // (12, 64, 32)
    k_gateup<<<g3, 256, 0, stream>>>(xbf, gw, uw, offsets, perm, h);

    dim3 g4(H_DIM / DN_BN, NPAIR / DN_BM, E_NUM);   // (16, 64, 32)
    k_down<<<g4, 256, 0, stream>>>(dw, offsets, pairw, perm, h, out);
}